// Round 7
// baseline (999.243 us; speedup 1.0000x reference)
//
#include <hip/hip_runtime.h>

#define N_NODES 100000
#define N_EDGES 1250000
#define D 64

#define BIN_SHIFT 9
#define BIN_NODES 512
#define NBINS ((N_NODES + BIN_NODES - 1) >> BIN_SHIFT)   // 196
#define BIN_CAP 8192   // mean 6377, sigma ~80 -> 8192 is >20 sigma safe

// ---- bf16 helpers (finite values only) ----
__device__ inline unsigned short f2bf(float f) {
    unsigned int u = __float_as_uint(f);
    unsigned int r = (u + 0x7fffu + ((u >> 16) & 1u)) >> 16;
    return (unsigned short)r;
}
__device__ inline float4 unpack_bf4(uint2 u) {
    float4 f;
    f.x = __uint_as_float(u.x << 16);
    f.y = __uint_as_float(u.x & 0xffff0000u);
    f.z = __uint_as_float(u.y << 16);
    f.w = __uint_as_float(u.y & 0xffff0000u);
    return f;
}

// ---------------- x fp32 -> bf16, fused with bin-counter zeroing ----------------
__global__ __launch_bounds__(256)
void convert_zero_kernel(const float4* __restrict__ xin, ushort4* __restrict__ xb,
                         int n4, int* __restrict__ bin_cnt) {
    int i = blockIdx.x * 256 + threadIdx.x;
    if (i < n4) {
        float4 v = xin[i];
        ushort4 u;
        u.x = f2bf(v.x); u.y = f2bf(v.y); u.z = f2bf(v.z); u.w = f2bf(v.w);
        xb[i] = u;
    }
    if (i < NBINS) bin_cnt[i] = 0;
}

// ---------------- pass 1: bin edges by dst>>9 (2 edges/thread) ----------------
__global__ __launch_bounds__(256)
void bin_kernel(const int2* __restrict__ src2, const int2* __restrict__ dst2,
                int* __restrict__ bin_cnt, int* __restrict__ bins) {
    int i = blockIdx.x * 256 + threadIdx.x;
    if (i < N_EDGES / 2) {
        int2 s = src2[i];
        int2 d = dst2[i];
        int b0 = d.x >> BIN_SHIFT;
        int p0 = atomicAdd(&bin_cnt[b0], 1);
        if (p0 < BIN_CAP)
            bins[(size_t)b0 * BIN_CAP + p0] = (s.x << BIN_SHIFT) | (d.x & (BIN_NODES - 1));
        int b1 = d.y >> BIN_SHIFT;
        int p1 = atomicAdd(&bin_cnt[b1], 1);
        if (p1 < BIN_CAP)
            bins[(size_t)b1 * BIN_CAP + p1] = (s.y << BIN_SHIFT) | (d.y & (BIN_NODES - 1));
    }
}

// ---------------- exclusive scan of bin counts (1 block) ----------------
__global__ __launch_bounds__(256)
void scan_bins_kernel(const int* __restrict__ bin_cnt, int* __restrict__ bin_start) {
    __shared__ int s[256];
    int t = threadIdx.x;
    int c = (t < NBINS) ? bin_cnt[t] : 0;
    int v = (c < BIN_CAP) ? c : BIN_CAP;
    s[t] = v;
    __syncthreads();
    for (int off = 1; off < 256; off <<= 1) {
        int x = (t >= off) ? s[t - off] : 0;
        __syncthreads();
        s[t] += x;
        __syncthreads();
    }
    if (t < NBINS) bin_start[t] = s[t] - v;   // exclusive
}

// ---------------- pass 2: per-bin LDS counting sort -> CSR ----------------
// block = bin. LDS hist over 512 local nodes, scan, scatter into staged
// buffer, contiguous coalesced write to sorted_src; emits deg + cursor_end.
__global__ __launch_bounds__(256)
void bin_sort_kernel(const int* __restrict__ bins, const int* __restrict__ bin_cnt,
                     const int* __restrict__ bin_start,
                     int* __restrict__ sorted_src,
                     int* __restrict__ deg_out, int* __restrict__ cend_out) {
    __shared__ int hist[BIN_NODES];
    __shared__ int cur[BIN_NODES];
    __shared__ int pscan[256];
    __shared__ int stage[BIN_CAP];

    const int b = blockIdx.x;
    const int t = threadIdx.x;
    int cnt = bin_cnt[b]; if (cnt > BIN_CAP) cnt = BIN_CAP;
    const int base = bin_start[b];
    const int nb0 = b << BIN_SHIFT;
    const int nn = (N_NODES - nb0 < BIN_NODES) ? (N_NODES - nb0) : BIN_NODES;
    const int* __restrict__ mybin = bins + (size_t)b * BIN_CAP;

    hist[t] = 0; hist[t + 256] = 0;
    __syncthreads();

    // phase 1: local histogram
    for (int i = t; i < cnt; i += 256)
        atomicAdd(&hist[mybin[i] & (BIN_NODES - 1)], 1);
    __syncthreads();

    // exclusive scan of hist[0..511]: thread t owns elements 2t, 2t+1
    int h0 = hist[2 * t], h1 = hist[2 * t + 1];
    int pv = h0 + h1;
    pscan[t] = pv;
    __syncthreads();
    for (int off = 1; off < 256; off <<= 1) {
        int x = (t >= off) ? pscan[t - off] : 0;
        __syncthreads();
        pscan[t] += x;
        __syncthreads();
    }
    int pairExcl = pscan[t] - pv;
    cur[2 * t] = pairExcl;
    cur[2 * t + 1] = pairExcl + h0;
    // emit deg / cursor_end for local nodes 2t, 2t+1
    if (2 * t < nn) {
        deg_out[nb0 + 2 * t] = h0;
        cend_out[nb0 + 2 * t] = base + pairExcl + h0;
    }
    if (2 * t + 1 < nn) {
        deg_out[nb0 + 2 * t + 1] = h1;
        cend_out[nb0 + 2 * t + 1] = base + pairExcl + h0 + h1;
    }
    __syncthreads();

    // phase 2: scatter srcs into staged buffer at local positions
    for (int i = t; i < cnt; i += 256) {
        int p = mybin[i];
        int pos = atomicAdd(&cur[p & (BIN_NODES - 1)], 1);
        stage[pos] = p >> BIN_SHIFT;   // src (non-negative, logical shift ok)
    }
    __syncthreads();

    // phase 3: contiguous coalesced write
    for (int i = t; i < cnt; i += 256)
        sorted_src[base + i] = stage[i];
}

// ---------------- fused layer: gather-mean + (mean@Wl + b + x@Wr) ----------------
// bf16 input. Quad-edge gather: uint2 (4 bf16) per lane, 16 lanes/row,
// lane quarter q handles edge 4t+q (selected via one ds_bpermute shfl).
// Cross-quarter combine: shfl_xor(16) + shfl_xor(32). 17.4 KB LDS, 8 blocks/CU.
template <typename TOUT>
__global__ __launch_bounds__(256, 8)
void fused_layer_kernel(const unsigned short* __restrict__ xin,   // bf16 [N,D]
                        const int* __restrict__ cursor_end,
                        const int* __restrict__ deg,
                        const int* __restrict__ sorted_src,
                        const float* __restrict__ Wl,
                        const float* __restrict__ bl,
                        const float* __restrict__ Wr,
                        TOUT* __restrict__ out,
                        int relu) {
    __shared__ float sM[32][68];
    __shared__ float sX[32][68];

    const uint2* __restrict__ xin64 = (const uint2*)xin;   // row = 16 uint2

    const int tid = threadIdx.x;
    const int row0 = blockIdx.x * 32;

    const int wave = tid >> 6;
    const int lane = tid & 63;
    const int q  = lane >> 4;        // quarter: handles edges 4t+q
    const int f2 = lane & 15;        // uint2 index within row (features f2*4..f2*4+3)

    for (int r = wave; r < 32; r += 4) {
        int n = row0 + r;            // grid is exactly N_NODES/32 -> n < N_NODES
        float4 a = make_float4(0.f, 0.f, 0.f, 0.f);
        int dg = deg[n];
        int st = cursor_end[n] - dg;
        float4 xv = unpack_bf4(xin64[(size_t)n * 16 + f2]);

        for (int base = 0; base < dg; base += 64) {
            int m = dg - base; if (m > 64) m = 64;
            int idx = 0;
            if (lane < m) idx = sorted_src[st + base + lane];
            int quads = m >> 2;
            float4 acc0 = make_float4(0.f, 0.f, 0.f, 0.f);
            float4 acc1 = make_float4(0.f, 0.f, 0.f, 0.f);
            int t = 0;
            for (; t + 2 <= quads; t += 2) {
                int sA = __shfl(idx, 4 * t + q);
                int sB = __shfl(idx, 4 * t + 4 + q);
                float4 fA = unpack_bf4(xin64[(size_t)sA * 16 + f2]);
                float4 fB = unpack_bf4(xin64[(size_t)sB * 16 + f2]);
                acc0.x += fA.x; acc0.y += fA.y; acc0.z += fA.z; acc0.w += fA.w;
                acc1.x += fB.x; acc1.y += fB.y; acc1.z += fB.z; acc1.w += fB.w;
            }
            if (t < quads) {
                int sA = __shfl(idx, 4 * t + q);
                float4 fA = unpack_bf4(xin64[(size_t)sA * 16 + f2]);
                acc0.x += fA.x; acc0.y += fA.y; acc0.z += fA.z; acc0.w += fA.w;
            }
            // tail (<=3 edges): quarter 0 only
            for (int e = quads * 4; e < m; ++e) {
                int s = __builtin_amdgcn_readlane(idx, e);
                if (q == 0) {
                    float4 f = unpack_bf4(xin64[(size_t)s * 16 + f2]);
                    acc1.x += f.x; acc1.y += f.y; acc1.z += f.z; acc1.w += f.w;
                }
            }
            a.x += acc0.x + acc1.x; a.y += acc0.y + acc1.y;
            a.z += acc0.z + acc1.z; a.w += acc0.w + acc1.w;
        }

        // combine quarters: lanes l, l+16, l+32, l+48 hold same features
        a.x += __shfl_xor(a.x, 16); a.y += __shfl_xor(a.y, 16);
        a.z += __shfl_xor(a.z, 16); a.w += __shfl_xor(a.w, 16);
        a.x += __shfl_xor(a.x, 32); a.y += __shfl_xor(a.y, 32);
        a.z += __shfl_xor(a.z, 32); a.w += __shfl_xor(a.w, 32);

        float inv = 1.0f / (float)(dg > 0 ? dg : 1);
        if (q == 0) {
            *(float4*)&sM[r][f2 * 4] =
                make_float4(a.x * inv, a.y * inv, a.z * inv, a.w * inv);
            *(float4*)&sX[r][f2 * 4] = xv;
        }
    }
    __syncthreads();

    // GEMM phase: thread = 2 rows x 4 cols; W read from global (L1/L2 resident)
    const int tx = tid & 15, ty = tid >> 4;   // ty 0..15
    const int j0 = tx * 4;
    const int i0 = ty * 2;

    float acc[2][4];
    float4 b4 = *(const float4*)&bl[j0];
#pragma unroll
    for (int i = 0; i < 2; ++i) {
        acc[i][0] = b4.x; acc[i][1] = b4.y; acc[i][2] = b4.z; acc[i][3] = b4.w;
    }

    for (int k = 0; k < 64; k += 4) {
        float4 wl[4], wr[4];
#pragma unroll
        for (int kk = 0; kk < 4; ++kk) {
            wl[kk] = *(const float4*)&Wl[(k + kk) * D + j0];
            wr[kk] = *(const float4*)&Wr[(k + kk) * D + j0];
        }
#pragma unroll
        for (int i = 0; i < 2; ++i) {
            float4 m  = *(const float4*)&sM[i0 + i][k];
            float4 xv = *(const float4*)&sX[i0 + i][k];
            float mk[4] = {m.x, m.y, m.z, m.w};
            float xk[4] = {xv.x, xv.y, xv.z, xv.w};
#pragma unroll
            for (int kk = 0; kk < 4; ++kk) {
                acc[i][0] += mk[kk] * wl[kk].x + xk[kk] * wr[kk].x;
                acc[i][1] += mk[kk] * wl[kk].y + xk[kk] * wr[kk].y;
                acc[i][2] += mk[kk] * wl[kk].z + xk[kk] * wr[kk].z;
                acc[i][3] += mk[kk] * wl[kk].w + xk[kk] * wr[kk].w;
            }
        }
    }

#pragma unroll
    for (int i = 0; i < 2; ++i) {
        int n = row0 + i0 + i;
        if (n < N_NODES) {
            float o[4];
#pragma unroll
            for (int j = 0; j < 4; ++j)
                o[j] = relu ? fmaxf(acc[i][j], 0.f) : acc[i][j];
            if constexpr (__hip_internal::is_same<TOUT, unsigned short>::value) {
                ushort4 u;
                u.x = f2bf(o[0]); u.y = f2bf(o[1]); u.z = f2bf(o[2]); u.w = f2bf(o[3]);
                *(ushort4*)&out[(size_t)n * D + j0] = u;
            } else {
                float4 f;
                f.x = o[0]; f.y = o[1]; f.z = o[2]; f.w = o[3];
                *(float4*)&out[(size_t)n * D + j0] = f;
            }
        }
    }
}

extern "C" void kernel_launch(void* const* d_in, const int* in_sizes, int n_in,
                              void* d_out, int out_size, void* d_ws, size_t ws_size,
                              hipStream_t stream) {
    const float* x   = (const float*)d_in[0];
    const int*   ei  = (const int*)d_in[1];
    const float* Wl1 = (const float*)d_in[2];
    const float* b1  = (const float*)d_in[3];
    const float* Wr1 = (const float*)d_in[4];
    const float* Wl2 = (const float*)d_in[5];
    const float* b2  = (const float*)d_in[6];
    const float* Wr2 = (const float*)d_in[7];

    const int* src = ei;
    const int* dst = ei + N_EDGES;

    // ws layout (ints):
    // bins[NBINS*BIN_CAP] | bin_cnt[256] | bin_start[256] | deg[N] | cend[N] |
    // sorted_src[E] | h_bf16[N*D]
    int* bins       = (int*)d_ws;
    int* bin_cnt    = bins + (size_t)NBINS * BIN_CAP;
    int* bin_start  = bin_cnt + 256;
    int* deg        = bin_start + 256;
    int* cend       = deg + N_NODES;
    int* sorted_src = cend + N_NODES;
    unsigned short* h = (unsigned short*)(sorted_src + N_EDGES);   // [N, D] bf16
    float* out = (float*)d_out;
    // xb (bf16 x) lives in d_out: dead until layer 2 fully rewrites d_out from h.
    unsigned short* xb = (unsigned short*)d_out;

    const int dense_blocks = N_NODES / 32;   // exactly 3125
    const int conv4 = N_NODES * D / 4;
    const int bin_blocks = (N_EDGES / 2 + 255) / 256;

    // x -> bf16 (into d_out scratch) + zero bin counters
    convert_zero_kernel<<<(conv4 + 255) / 256, 256, 0, stream>>>(
        (const float4*)x, (ushort4*)xb, conv4, bin_cnt);

    // build CSR: coarse bin -> scan -> per-bin LDS sort
    bin_kernel<<<bin_blocks, 256, 0, stream>>>((const int2*)src, (const int2*)dst,
                                               bin_cnt, bins);
    scan_bins_kernel<<<1, 256, 0, stream>>>(bin_cnt, bin_start);
    bin_sort_kernel<<<NBINS, 256, 0, stream>>>(bins, bin_cnt, bin_start,
                                               sorted_src, deg, cend);

    // layer 1: xb (bf16, in d_out) -> h (bf16, ws)
    fused_layer_kernel<unsigned short><<<dense_blocks, 256, 0, stream>>>(
        xb, cend, deg, sorted_src, Wl1, b1, Wr1, h, /*relu=*/1);
    // layer 2: h (bf16) -> out (fp32, d_out) — overwrites xb entirely
    fused_layer_kernel<float><<<dense_blocks, 256, 0, stream>>>(
        h, cend, deg, sorted_src, Wl2, b2, Wr2, out, /*relu=*/0);
}

// Round 8
// 315.427 us; speedup vs baseline: 3.1679x; 3.1679x over previous
//
#include <hip/hip_runtime.h>

#define N_NODES 100000
#define N_EDGES 1250000
#define D 64

#define BIN_SHIFT 9
#define BIN_NODES 512
#define NBINS ((N_NODES + BIN_NODES - 1) >> BIN_SHIFT)   // 196
#define BIN_CAP 8192   // mean 6377, sigma ~80 -> 8192 is >20 sigma safe
#define CHUNK 4096     // edges per bin_kernel block

// ---- bf16 helpers (finite values only) ----
__device__ inline unsigned short f2bf(float f) {
    unsigned int u = __float_as_uint(f);
    unsigned int r = (u + 0x7fffu + ((u >> 16) & 1u)) >> 16;
    return (unsigned short)r;
}
__device__ inline float4 unpack_bf4(uint2 u) {
    float4 f;
    f.x = __uint_as_float(u.x << 16);
    f.y = __uint_as_float(u.x & 0xffff0000u);
    f.z = __uint_as_float(u.y << 16);
    f.w = __uint_as_float(u.y & 0xffff0000u);
    return f;
}

// ---------------- x fp32 -> bf16, fused with bin-counter zeroing ----------------
__global__ __launch_bounds__(256)
void convert_zero_kernel(const float4* __restrict__ xin, ushort4* __restrict__ xb,
                         int n4, int* __restrict__ bin_cnt) {
    int i = blockIdx.x * 256 + threadIdx.x;
    if (i < n4) {
        float4 v = xin[i];
        ushort4 u;
        u.x = f2bf(v.x); u.y = f2bf(v.y); u.z = f2bf(v.z); u.w = f2bf(v.w);
        xb[i] = u;
    }
    if (i < NBINS) bin_cnt[i] = 0;
}

// ---------------- pass 1: LDS-aggregated binning by dst>>9 ----------------
// Block = 4096 edges. LDS hist over 196 bins -> ONE global atomic per
// (bin, block) reserving a contiguous range -> LDS-staged, bin-sorted,
// near-coalesced global write. Global atomics: 306*196 ~= 60K (vs 1.25M).
__global__ __launch_bounds__(256)
void bin_kernel(const int* __restrict__ src, const int* __restrict__ dst,
                int* __restrict__ bin_cnt, int* __restrict__ bins) {
    __shared__ int lhist[NBINS];
    __shared__ int lstart[NBINS];
    __shared__ int lbase[NBINS];
    __shared__ int lcur[NBINS];
    __shared__ int pscan[256];
    __shared__ int sval[CHUNK];
    __shared__ int sdst[CHUNK];

    const int t = threadIdx.x;
    const int e0 = blockIdx.x * CHUNK;
    int cnt = N_EDGES - e0; if (cnt > CHUNK) cnt = CHUNK;

    for (int i = t; i < NBINS; i += 256) lhist[i] = 0;
    __syncthreads();

    // local histogram
    for (int i = t; i < cnt; i += 256)
        atomicAdd(&lhist[dst[e0 + i] >> BIN_SHIFT], 1);
    __syncthreads();

    // exclusive scan over bins (NBINS <= 256) + one global reserve per bin
    int h = (t < NBINS) ? lhist[t] : 0;
    pscan[t] = h;
    __syncthreads();
    for (int off = 1; off < 256; off <<= 1) {
        int x = (t >= off) ? pscan[t - off] : 0;
        __syncthreads();
        pscan[t] += x;
        __syncthreads();
    }
    if (t < NBINS) {
        int excl = pscan[t] - h;
        lstart[t] = excl;
        lcur[t] = excl;
        lbase[t] = (h > 0) ? atomicAdd(&bin_cnt[t], h) : 0;
    }
    __syncthreads();

    // scatter into LDS stage (bin-sorted order) + compute global dest
    for (int i = t; i < cnt; i += 256) {
        int d = dst[e0 + i];
        int s = src[e0 + i];
        int b = d >> BIN_SHIFT;
        int slot = atomicAdd(&lcur[b], 1);
        int rank = slot - lstart[b];
        sval[slot] = (s << BIN_SHIFT) | (d & (BIN_NODES - 1));
        int gp = lbase[b] + rank;
        sdst[slot] = (gp < BIN_CAP) ? (b * BIN_CAP + gp) : -1;
    }
    __syncthreads();

    // near-coalesced write: consecutive slots -> consecutive dests per bin run
    for (int i = t; i < cnt; i += 256) {
        int dd = sdst[i];
        if (dd >= 0) bins[dd] = sval[i];
    }
}

// ---------------- exclusive scan of bin counts (1 block) ----------------
__global__ __launch_bounds__(256)
void scan_bins_kernel(const int* __restrict__ bin_cnt, int* __restrict__ bin_start) {
    __shared__ int s[256];
    int t = threadIdx.x;
    int c = (t < NBINS) ? bin_cnt[t] : 0;
    int v = (c < BIN_CAP) ? c : BIN_CAP;
    s[t] = v;
    __syncthreads();
    for (int off = 1; off < 256; off <<= 1) {
        int x = (t >= off) ? s[t - off] : 0;
        __syncthreads();
        s[t] += x;
        __syncthreads();
    }
    if (t < NBINS) bin_start[t] = s[t] - v;   // exclusive
}

// ---------------- pass 2: per-bin LDS counting sort -> CSR ----------------
__global__ __launch_bounds__(256)
void bin_sort_kernel(const int* __restrict__ bins, const int* __restrict__ bin_cnt,
                     const int* __restrict__ bin_start,
                     int* __restrict__ sorted_src,
                     int* __restrict__ deg_out, int* __restrict__ cend_out) {
    __shared__ int hist[BIN_NODES];
    __shared__ int cur[BIN_NODES];
    __shared__ int pscan[256];
    __shared__ int stage[BIN_CAP];

    const int b = blockIdx.x;
    const int t = threadIdx.x;
    int cnt = bin_cnt[b]; if (cnt > BIN_CAP) cnt = BIN_CAP;
    const int base = bin_start[b];
    const int nb0 = b << BIN_SHIFT;
    const int nn = (N_NODES - nb0 < BIN_NODES) ? (N_NODES - nb0) : BIN_NODES;
    const int* __restrict__ mybin = bins + (size_t)b * BIN_CAP;

    hist[t] = 0; hist[t + 256] = 0;
    __syncthreads();

    for (int i = t; i < cnt; i += 256)
        atomicAdd(&hist[mybin[i] & (BIN_NODES - 1)], 1);
    __syncthreads();

    int h0 = hist[2 * t], h1 = hist[2 * t + 1];
    int pv = h0 + h1;
    pscan[t] = pv;
    __syncthreads();
    for (int off = 1; off < 256; off <<= 1) {
        int x = (t >= off) ? pscan[t - off] : 0;
        __syncthreads();
        pscan[t] += x;
        __syncthreads();
    }
    int pairExcl = pscan[t] - pv;
    cur[2 * t] = pairExcl;
    cur[2 * t + 1] = pairExcl + h0;
    if (2 * t < nn) {
        deg_out[nb0 + 2 * t] = h0;
        cend_out[nb0 + 2 * t] = base + pairExcl + h0;
    }
    if (2 * t + 1 < nn) {
        deg_out[nb0 + 2 * t + 1] = h1;
        cend_out[nb0 + 2 * t + 1] = base + pairExcl + h0 + h1;
    }
    __syncthreads();

    for (int i = t; i < cnt; i += 256) {
        int p = mybin[i];
        int pos = atomicAdd(&cur[p & (BIN_NODES - 1)], 1);
        stage[pos] = p >> BIN_SHIFT;
    }
    __syncthreads();

    for (int i = t; i < cnt; i += 256)
        sorted_src[base + i] = stage[i];
}

// ---------------- fused layer: gather-mean + (mean@Wl + b + x@Wr) ----------------
// bf16 input. Quad-edge gather: uint2 (4 bf16) per lane, 16 lanes/row,
// lane quarter q handles edge 4t+q (selected via one ds_bpermute shfl).
// Cross-quarter combine: shfl_xor(16) + shfl_xor(32). 17.4 KB LDS, 8 blocks/CU.
template <typename TOUT>
__global__ __launch_bounds__(256, 8)
void fused_layer_kernel(const unsigned short* __restrict__ xin,   // bf16 [N,D]
                        const int* __restrict__ cursor_end,
                        const int* __restrict__ deg,
                        const int* __restrict__ sorted_src,
                        const float* __restrict__ Wl,
                        const float* __restrict__ bl,
                        const float* __restrict__ Wr,
                        TOUT* __restrict__ out,
                        int relu) {
    __shared__ float sM[32][68];
    __shared__ float sX[32][68];

    const uint2* __restrict__ xin64 = (const uint2*)xin;   // row = 16 uint2

    const int tid = threadIdx.x;
    const int row0 = blockIdx.x * 32;

    const int wave = tid >> 6;
    const int lane = tid & 63;
    const int q  = lane >> 4;        // quarter: handles edges 4t+q
    const int f2 = lane & 15;        // uint2 index within row

    for (int r = wave; r < 32; r += 4) {
        int n = row0 + r;
        float4 a = make_float4(0.f, 0.f, 0.f, 0.f);
        int dg = deg[n];
        int st = cursor_end[n] - dg;
        float4 xv = unpack_bf4(xin64[(size_t)n * 16 + f2]);

        for (int base = 0; base < dg; base += 64) {
            int m = dg - base; if (m > 64) m = 64;
            int idx = 0;
            if (lane < m) idx = sorted_src[st + base + lane];
            int quads = m >> 2;
            float4 acc0 = make_float4(0.f, 0.f, 0.f, 0.f);
            float4 acc1 = make_float4(0.f, 0.f, 0.f, 0.f);
            int t = 0;
            for (; t + 2 <= quads; t += 2) {
                int sA = __shfl(idx, 4 * t + q);
                int sB = __shfl(idx, 4 * t + 4 + q);
                float4 fA = unpack_bf4(xin64[(size_t)sA * 16 + f2]);
                float4 fB = unpack_bf4(xin64[(size_t)sB * 16 + f2]);
                acc0.x += fA.x; acc0.y += fA.y; acc0.z += fA.z; acc0.w += fA.w;
                acc1.x += fB.x; acc1.y += fB.y; acc1.z += fB.z; acc1.w += fB.w;
            }
            if (t < quads) {
                int sA = __shfl(idx, 4 * t + q);
                float4 fA = unpack_bf4(xin64[(size_t)sA * 16 + f2]);
                acc0.x += fA.x; acc0.y += fA.y; acc0.z += fA.z; acc0.w += fA.w;
            }
            for (int e = quads * 4; e < m; ++e) {
                int s = __builtin_amdgcn_readlane(idx, e);
                if (q == 0) {
                    float4 f = unpack_bf4(xin64[(size_t)s * 16 + f2]);
                    acc1.x += f.x; acc1.y += f.y; acc1.z += f.z; acc1.w += f.w;
                }
            }
            a.x += acc0.x + acc1.x; a.y += acc0.y + acc1.y;
            a.z += acc0.z + acc1.z; a.w += acc0.w + acc1.w;
        }

        a.x += __shfl_xor(a.x, 16); a.y += __shfl_xor(a.y, 16);
        a.z += __shfl_xor(a.z, 16); a.w += __shfl_xor(a.w, 16);
        a.x += __shfl_xor(a.x, 32); a.y += __shfl_xor(a.y, 32);
        a.z += __shfl_xor(a.z, 32); a.w += __shfl_xor(a.w, 32);

        float inv = 1.0f / (float)(dg > 0 ? dg : 1);
        if (q == 0) {
            *(float4*)&sM[r][f2 * 4] =
                make_float4(a.x * inv, a.y * inv, a.z * inv, a.w * inv);
            *(float4*)&sX[r][f2 * 4] = xv;
        }
    }
    __syncthreads();

    const int tx = tid & 15, ty = tid >> 4;
    const int j0 = tx * 4;
    const int i0 = ty * 2;

    float acc[2][4];
    float4 b4 = *(const float4*)&bl[j0];
#pragma unroll
    for (int i = 0; i < 2; ++i) {
        acc[i][0] = b4.x; acc[i][1] = b4.y; acc[i][2] = b4.z; acc[i][3] = b4.w;
    }

    for (int k = 0; k < 64; k += 4) {
        float4 wl[4], wr[4];
#pragma unroll
        for (int kk = 0; kk < 4; ++kk) {
            wl[kk] = *(const float4*)&Wl[(k + kk) * D + j0];
            wr[kk] = *(const float4*)&Wr[(k + kk) * D + j0];
        }
#pragma unroll
        for (int i = 0; i < 2; ++i) {
            float4 m  = *(const float4*)&sM[i0 + i][k];
            float4 xv = *(const float4*)&sX[i0 + i][k];
            float mk[4] = {m.x, m.y, m.z, m.w};
            float xk[4] = {xv.x, xv.y, xv.z, xv.w};
#pragma unroll
            for (int kk = 0; kk < 4; ++kk) {
                acc[i][0] += mk[kk] * wl[kk].x + xk[kk] * wr[kk].x;
                acc[i][1] += mk[kk] * wl[kk].y + xk[kk] * wr[kk].y;
                acc[i][2] += mk[kk] * wl[kk].z + xk[kk] * wr[kk].z;
                acc[i][3] += mk[kk] * wl[kk].w + xk[kk] * wr[kk].w;
            }
        }
    }

#pragma unroll
    for (int i = 0; i < 2; ++i) {
        int n = row0 + i0 + i;
        if (n < N_NODES) {
            float o[4];
#pragma unroll
            for (int j = 0; j < 4; ++j)
                o[j] = relu ? fmaxf(acc[i][j], 0.f) : acc[i][j];
            if constexpr (__hip_internal::is_same<TOUT, unsigned short>::value) {
                ushort4 u;
                u.x = f2bf(o[0]); u.y = f2bf(o[1]); u.z = f2bf(o[2]); u.w = f2bf(o[3]);
                *(ushort4*)&out[(size_t)n * D + j0] = u;
            } else {
                float4 f;
                f.x = o[0]; f.y = o[1]; f.z = o[2]; f.w = o[3];
                *(float4*)&out[(size_t)n * D + j0] = f;
            }
        }
    }
}

extern "C" void kernel_launch(void* const* d_in, const int* in_sizes, int n_in,
                              void* d_out, int out_size, void* d_ws, size_t ws_size,
                              hipStream_t stream) {
    const float* x   = (const float*)d_in[0];
    const int*   ei  = (const int*)d_in[1];
    const float* Wl1 = (const float*)d_in[2];
    const float* b1  = (const float*)d_in[3];
    const float* Wr1 = (const float*)d_in[4];
    const float* Wl2 = (const float*)d_in[5];
    const float* b2  = (const float*)d_in[6];
    const float* Wr2 = (const float*)d_in[7];

    const int* src = ei;
    const int* dst = ei + N_EDGES;

    // ws layout (ints):
    // bins[NBINS*BIN_CAP] | bin_cnt[256] | bin_start[256] | deg[N] | cend[N] |
    // sorted_src[E] | h_bf16[N*D]
    int* bins       = (int*)d_ws;
    int* bin_cnt    = bins + (size_t)NBINS * BIN_CAP;
    int* bin_start  = bin_cnt + 256;
    int* deg        = bin_start + 256;
    int* cend       = deg + N_NODES;
    int* sorted_src = cend + N_NODES;
    unsigned short* h = (unsigned short*)(sorted_src + N_EDGES);   // [N, D] bf16
    float* out = (float*)d_out;
    unsigned short* xb = (unsigned short*)d_out;   // bf16 x scratch in d_out

    const int dense_blocks = N_NODES / 32;   // exactly 3125
    const int conv4 = N_NODES * D / 4;
    const int bin_blocks = (N_EDGES + CHUNK - 1) / CHUNK;   // 306

    convert_zero_kernel<<<(conv4 + 255) / 256, 256, 0, stream>>>(
        (const float4*)x, (ushort4*)xb, conv4, bin_cnt);

    bin_kernel<<<bin_blocks, 256, 0, stream>>>(src, dst, bin_cnt, bins);
    scan_bins_kernel<<<1, 256, 0, stream>>>(bin_cnt, bin_start);
    bin_sort_kernel<<<NBINS, 256, 0, stream>>>(bins, bin_cnt, bin_start,
                                               sorted_src, deg, cend);

    fused_layer_kernel<unsigned short><<<dense_blocks, 256, 0, stream>>>(
        xb, cend, deg, sorted_src, Wl1, b1, Wr1, h, /*relu=*/1);
    fused_layer_kernel<float><<<dense_blocks, 256, 0, stream>>>(
        h, cend, deg, sorted_src, Wl2, b2, Wr2, out, /*relu=*/0);
}

// Round 9
// 290.855 us; speedup vs baseline: 3.4355x; 1.0845x over previous
//
#include <hip/hip_runtime.h>

#define N_NODES 100000
#define N_EDGES 1250000
#define D 64

#define BIN_SHIFT 9
#define BIN_NODES 512
#define NBINS ((N_NODES + BIN_NODES - 1) >> BIN_SHIFT)   // 196
#define BIN_CAP 7168     // mean 6377, sigma ~80 -> ~10 sigma safe
#define SLAB 8704        // BIN_CAP + 3*BIN_NODES (worst-case padding)
#define CHUNK 4096       // edges per bin_kernel block
#define ZERO_NODE N_NODES   // virtual all-zero row for padding

// ---- bf16 helpers (finite values only) ----
__device__ inline unsigned short f2bf(float f) {
    unsigned int u = __float_as_uint(f);
    unsigned int r = (u + 0x7fffu + ((u >> 16) & 1u)) >> 16;
    return (unsigned short)r;
}
__device__ inline float4 unpack_bf4(uint2 u) {
    float4 f;
    f.x = __uint_as_float(u.x << 16);
    f.y = __uint_as_float(u.x & 0xffff0000u);
    f.z = __uint_as_float(u.y << 16);
    f.w = __uint_as_float(u.y & 0xffff0000u);
    return f;
}

// ---------------- x fp32 -> bf16 + zero bin counters + zero virtual rows ----------
__global__ __launch_bounds__(256)
void convert_zero_kernel(const float4* __restrict__ xin, ushort4* __restrict__ xb,
                         int n4, int* __restrict__ bin_cnt,
                         unsigned int* __restrict__ xb_zrow,
                         unsigned int* __restrict__ h_zrow) {
    int i = blockIdx.x * 256 + threadIdx.x;
    if (i < n4) {
        float4 v = xin[i];
        ushort4 u;
        u.x = f2bf(v.x); u.y = f2bf(v.y); u.z = f2bf(v.z); u.w = f2bf(v.w);
        xb[i] = u;
    }
    if (i < NBINS) bin_cnt[i] = 0;
    if (i < 32) { xb_zrow[i] = 0u; h_zrow[i] = 0u; }   // 64 bf16 = 32 uints each
}

// ---------------- pass 1: LDS-aggregated binning by dst>>9 ----------------
__global__ __launch_bounds__(256)
void bin_kernel(const int* __restrict__ src, const int* __restrict__ dst,
                int* __restrict__ bin_cnt, int* __restrict__ slabs) {
    __shared__ int lhist[NBINS];
    __shared__ int lstart[NBINS];
    __shared__ int lbase[NBINS];
    __shared__ int lcur[NBINS];
    __shared__ int pscan[256];
    __shared__ int sval[CHUNK];
    __shared__ int sdst[CHUNK];

    const int t = threadIdx.x;
    const int e0 = blockIdx.x * CHUNK;
    int cnt = N_EDGES - e0; if (cnt > CHUNK) cnt = CHUNK;

    for (int i = t; i < NBINS; i += 256) lhist[i] = 0;
    __syncthreads();

    for (int i = t; i < cnt; i += 256)
        atomicAdd(&lhist[dst[e0 + i] >> BIN_SHIFT], 1);
    __syncthreads();

    int h = (t < NBINS) ? lhist[t] : 0;
    pscan[t] = h;
    __syncthreads();
    for (int off = 1; off < 256; off <<= 1) {
        int x = (t >= off) ? pscan[t - off] : 0;
        __syncthreads();
        pscan[t] += x;
        __syncthreads();
    }
    if (t < NBINS) {
        int excl = pscan[t] - h;
        lstart[t] = excl;
        lcur[t] = excl;
        lbase[t] = (h > 0) ? atomicAdd(&bin_cnt[t], h) : 0;
    }
    __syncthreads();

    for (int i = t; i < cnt; i += 256) {
        int d = dst[e0 + i];
        int s = src[e0 + i];
        int b = d >> BIN_SHIFT;
        int slot = atomicAdd(&lcur[b], 1);
        int rank = slot - lstart[b];
        sval[slot] = (s << BIN_SHIFT) | (d & (BIN_NODES - 1));
        int gp = lbase[b] + rank;
        sdst[slot] = (gp < BIN_CAP) ? (b * SLAB + gp) : -1;
    }
    __syncthreads();

    for (int i = t; i < cnt; i += 256) {
        int dd = sdst[i];
        if (dd >= 0) slabs[dd] = sval[i];
    }
}

// ---------------- pass 2: per-bin LDS counting sort -> padded CSR (in place) ----
// Block = bin. Stage whole bin in LDS, hist, padded scan, write node-sorted
// srcs (padded to x4 with ZERO_NODE) back into the SAME slab. Emits deg +
// row_start (absolute, padded).
__global__ __launch_bounds__(256)
void bin_sort_kernel(int* __restrict__ slabs, const int* __restrict__ bin_cnt,
                     int* __restrict__ deg_out, int* __restrict__ rstart_out) {
    __shared__ int hist[BIN_NODES];
    __shared__ int cur[BIN_NODES];
    __shared__ int pscan[256];
    __shared__ int stage[BIN_CAP];

    const int b = blockIdx.x;
    const int t = threadIdx.x;
    int cnt = bin_cnt[b]; if (cnt > BIN_CAP) cnt = BIN_CAP;
    const int nb0 = b << BIN_SHIFT;
    const int nn = (N_NODES - nb0 < BIN_NODES) ? (N_NODES - nb0) : BIN_NODES;
    const int slab0 = b * SLAB;

    hist[t] = 0; hist[t + 256] = 0;
    __syncthreads();

    // stage bin + histogram
    for (int i = t; i < cnt; i += 256) {
        int p = slabs[slab0 + i];
        stage[i] = p;
        atomicAdd(&hist[p & (BIN_NODES - 1)], 1);
    }
    __syncthreads();

    // padded exclusive scan: thread t owns local nodes 2t, 2t+1
    int h0 = hist[2 * t], h1 = hist[2 * t + 1];
    int ph0 = (h0 + 3) & ~3, ph1 = (h1 + 3) & ~3;
    int pv = ph0 + ph1;
    pscan[t] = pv;
    __syncthreads();
    for (int off = 1; off < 256; off <<= 1) {
        int x = (t >= off) ? pscan[t - off] : 0;
        __syncthreads();
        pscan[t] += x;
        __syncthreads();
    }
    int pairExcl = pscan[t] - pv;
    int s0 = pairExcl, s1 = pairExcl + ph0;
    cur[2 * t] = s0;
    cur[2 * t + 1] = s1;
    if (2 * t < nn) {
        deg_out[nb0 + 2 * t] = h0;
        rstart_out[nb0 + 2 * t] = slab0 + s0;
        for (int i = h0; i < ph0; ++i) slabs[slab0 + s0 + i] = ZERO_NODE;
    }
    if (2 * t + 1 < nn) {
        deg_out[nb0 + 2 * t + 1] = h1;
        rstart_out[nb0 + 2 * t + 1] = slab0 + s1;
        for (int i = h1; i < ph1; ++i) slabs[slab0 + s1 + i] = ZERO_NODE;
    }
    __syncthreads();

    // scatter srcs from stage back into slab at padded positions
    for (int i = t; i < cnt; i += 256) {
        int p = stage[i];
        int pos = atomicAdd(&cur[p & (BIN_NODES - 1)], 1);
        slabs[slab0 + pos] = p >> BIN_SHIFT;
    }
}

// ---------------- fused layer: gather-mean + (mean@Wl + b + x@Wr) ----------------
// bf16 input. Quad-edge gather: uint2 (4 bf16) per lane, 16 lanes/row, lane
// quarter q handles edge 4t+q. Edge lists padded to x4 with ZERO_NODE (its
// row is zeros, L1-resident) -> no tail. 4-deep unroll. 17.4 KB LDS, 8 blk/CU.
template <typename TOUT>
__global__ __launch_bounds__(256, 8)
void fused_layer_kernel(const unsigned short* __restrict__ xin,   // bf16 [N+1,D]
                        const int* __restrict__ rstart,
                        const int* __restrict__ deg,
                        const int* __restrict__ sorted_src,
                        const float* __restrict__ Wl,
                        const float* __restrict__ bl,
                        const float* __restrict__ Wr,
                        TOUT* __restrict__ out,
                        int relu) {
    __shared__ float sM[32][68];
    __shared__ float sX[32][68];

    const uint2* __restrict__ xin64 = (const uint2*)xin;   // row = 16 uint2

    const int tid = threadIdx.x;
    const int row0 = blockIdx.x * 32;

    const int wave = tid >> 6;
    const int lane = tid & 63;
    const int q  = lane >> 4;
    const int f2 = lane & 15;

    for (int r = wave; r < 32; r += 4) {
        int n = row0 + r;
        float4 a = make_float4(0.f, 0.f, 0.f, 0.f);
        int dg = deg[n];
        int pdg = (dg + 3) & ~3;
        int st = rstart[n];
        float4 xv = unpack_bf4(xin64[(size_t)n * 16 + f2]);

        for (int base = 0; base < pdg; base += 64) {
            int m = pdg - base; if (m > 64) m = 64;
            int idx = 0;
            if (lane < m) idx = sorted_src[st + base + lane];
            int quads = m >> 2;
            float4 c0 = make_float4(0.f, 0.f, 0.f, 0.f);
            float4 c1 = make_float4(0.f, 0.f, 0.f, 0.f);
            float4 c2 = make_float4(0.f, 0.f, 0.f, 0.f);
            float4 c3 = make_float4(0.f, 0.f, 0.f, 0.f);
            int t = 0;
            for (; t + 4 <= quads; t += 4) {
                int sA = __shfl(idx, 4 * t + q);
                int sB = __shfl(idx, 4 * t + 4 + q);
                int sC = __shfl(idx, 4 * t + 8 + q);
                int sD = __shfl(idx, 4 * t + 12 + q);
                float4 fA = unpack_bf4(xin64[(size_t)sA * 16 + f2]);
                float4 fB = unpack_bf4(xin64[(size_t)sB * 16 + f2]);
                float4 fC = unpack_bf4(xin64[(size_t)sC * 16 + f2]);
                float4 fD = unpack_bf4(xin64[(size_t)sD * 16 + f2]);
                c0.x += fA.x; c0.y += fA.y; c0.z += fA.z; c0.w += fA.w;
                c1.x += fB.x; c1.y += fB.y; c1.z += fB.z; c1.w += fB.w;
                c2.x += fC.x; c2.y += fC.y; c2.z += fC.z; c2.w += fC.w;
                c3.x += fD.x; c3.y += fD.y; c3.z += fD.z; c3.w += fD.w;
            }
            for (; t + 2 <= quads; t += 2) {
                int sA = __shfl(idx, 4 * t + q);
                int sB = __shfl(idx, 4 * t + 4 + q);
                float4 fA = unpack_bf4(xin64[(size_t)sA * 16 + f2]);
                float4 fB = unpack_bf4(xin64[(size_t)sB * 16 + f2]);
                c0.x += fA.x; c0.y += fA.y; c0.z += fA.z; c0.w += fA.w;
                c1.x += fB.x; c1.y += fB.y; c1.z += fB.z; c1.w += fB.w;
            }
            for (; t < quads; ++t) {
                int sA = __shfl(idx, 4 * t + q);
                float4 fA = unpack_bf4(xin64[(size_t)sA * 16 + f2]);
                c0.x += fA.x; c0.y += fA.y; c0.z += fA.z; c0.w += fA.w;
            }
            a.x += (c0.x + c1.x) + (c2.x + c3.x);
            a.y += (c0.y + c1.y) + (c2.y + c3.y);
            a.z += (c0.z + c1.z) + (c2.z + c3.z);
            a.w += (c0.w + c1.w) + (c2.w + c3.w);
        }

        a.x += __shfl_xor(a.x, 16); a.y += __shfl_xor(a.y, 16);
        a.z += __shfl_xor(a.z, 16); a.w += __shfl_xor(a.w, 16);
        a.x += __shfl_xor(a.x, 32); a.y += __shfl_xor(a.y, 32);
        a.z += __shfl_xor(a.z, 32); a.w += __shfl_xor(a.w, 32);

        float inv = 1.0f / (float)(dg > 0 ? dg : 1);
        if (q == 0) {
            *(float4*)&sM[r][f2 * 4] =
                make_float4(a.x * inv, a.y * inv, a.z * inv, a.w * inv);
            *(float4*)&sX[r][f2 * 4] = xv;
        }
    }
    __syncthreads();

    const int tx = tid & 15, ty = tid >> 4;
    const int j0 = tx * 4;
    const int i0 = ty * 2;

    float acc[2][4];
    float4 b4 = *(const float4*)&bl[j0];
#pragma unroll
    for (int i = 0; i < 2; ++i) {
        acc[i][0] = b4.x; acc[i][1] = b4.y; acc[i][2] = b4.z; acc[i][3] = b4.w;
    }

    for (int k = 0; k < 64; k += 4) {
        float4 wl[4], wr[4];
#pragma unroll
        for (int kk = 0; kk < 4; ++kk) {
            wl[kk] = *(const float4*)&Wl[(k + kk) * D + j0];
            wr[kk] = *(const float4*)&Wr[(k + kk) * D + j0];
        }
#pragma unroll
        for (int i = 0; i < 2; ++i) {
            float4 m  = *(const float4*)&sM[i0 + i][k];
            float4 xv = *(const float4*)&sX[i0 + i][k];
            float mk[4] = {m.x, m.y, m.z, m.w};
            float xk[4] = {xv.x, xv.y, xv.z, xv.w};
#pragma unroll
            for (int kk = 0; kk < 4; ++kk) {
                acc[i][0] += mk[kk] * wl[kk].x + xk[kk] * wr[kk].x;
                acc[i][1] += mk[kk] * wl[kk].y + xk[kk] * wr[kk].y;
                acc[i][2] += mk[kk] * wl[kk].z + xk[kk] * wr[kk].z;
                acc[i][3] += mk[kk] * wl[kk].w + xk[kk] * wr[kk].w;
            }
        }
    }

#pragma unroll
    for (int i = 0; i < 2; ++i) {
        int n = row0 + i0 + i;
        float o[4];
#pragma unroll
        for (int j = 0; j < 4; ++j)
            o[j] = relu ? fmaxf(acc[i][j], 0.f) : acc[i][j];
        if constexpr (__hip_internal::is_same<TOUT, unsigned short>::value) {
            ushort4 u;
            u.x = f2bf(o[0]); u.y = f2bf(o[1]); u.z = f2bf(o[2]); u.w = f2bf(o[3]);
            *(ushort4*)&out[(size_t)n * D + j0] = u;
        } else {
            float4 f;
            f.x = o[0]; f.y = o[1]; f.z = o[2]; f.w = o[3];
            *(float4*)&out[(size_t)n * D + j0] = f;
        }
    }
}

extern "C" void kernel_launch(void* const* d_in, const int* in_sizes, int n_in,
                              void* d_out, int out_size, void* d_ws, size_t ws_size,
                              hipStream_t stream) {
    const float* x   = (const float*)d_in[0];
    const int*   ei  = (const int*)d_in[1];
    const float* Wl1 = (const float*)d_in[2];
    const float* b1  = (const float*)d_in[3];
    const float* Wr1 = (const float*)d_in[4];
    const float* Wl2 = (const float*)d_in[5];
    const float* b2  = (const float*)d_in[6];
    const float* Wr2 = (const float*)d_in[7];

    const int* src = ei;
    const int* dst = ei + N_EDGES;

    // ws layout (ints): slabs[196*8704] | bin_cnt[256] | deg[N] | rstart[N] |
    //                   h_bf16[(N+1)*D]   (~20.4 MB total)
    int* slabs   = (int*)d_ws;
    int* bin_cnt = slabs + (size_t)NBINS * SLAB;
    int* deg     = bin_cnt + 256;
    int* rstart  = deg + N_NODES;
    unsigned short* h = (unsigned short*)(rstart + N_NODES);   // [N+1, D] bf16
    float* out = (float*)d_out;
    unsigned short* xb = (unsigned short*)d_out;   // bf16 x scratch in d_out [N+1, D]

    const int dense_blocks = N_NODES / 32;   // 3125
    const int conv4 = N_NODES * D / 4;
    const int bin_blocks = (N_EDGES + CHUNK - 1) / CHUNK;   // 306

    convert_zero_kernel<<<(conv4 + 255) / 256, 256, 0, stream>>>(
        (const float4*)x, (ushort4*)xb, conv4, bin_cnt,
        (unsigned int*)(xb + (size_t)ZERO_NODE * D),
        (unsigned int*)(h + (size_t)ZERO_NODE * D));

    bin_kernel<<<bin_blocks, 256, 0, stream>>>(src, dst, bin_cnt, slabs);
    bin_sort_kernel<<<NBINS, 256, 0, stream>>>(slabs, bin_cnt, deg, rstart);

    fused_layer_kernel<unsigned short><<<dense_blocks, 256, 0, stream>>>(
        xb, rstart, deg, slabs, Wl1, b1, Wr1, h, /*relu=*/1);
    fused_layer_kernel<float><<<dense_blocks, 256, 0, stream>>>(
        h, rstart, deg, slabs, Wl2, b2, Wr2, out, /*relu=*/0);
}

// Round 10
// 220.712 us; speedup vs baseline: 4.5274x; 1.3178x over previous
//
#include <hip/hip_runtime.h>

#define N_NODES 100000
#define N_EDGES 1250000
#define D 64

#define BIN_SHIFT 9
#define BIN_NODES 512
#define NBINS ((N_NODES + BIN_NODES - 1) >> BIN_SHIFT)   // 196
#define BIN_CAP 7168     // mean 6377, sigma ~80 -> ~10 sigma safe
#define SLAB 8704        // BIN_CAP + 3*BIN_NODES (worst-case padding)
#define CHUNK 4096       // edges per bin_kernel block
#define ZERO_NODE N_NODES   // virtual all-zero row for padding

typedef __attribute__((ext_vector_type(8))) short short8;   // 8 bf16 (4 VGPRs)
typedef __attribute__((ext_vector_type(4))) float f32x4;    // MFMA acc

// ---- bf16 helpers (finite values only) ----
__device__ inline unsigned short f2bf(float f) {
    unsigned int u = __float_as_uint(f);
    unsigned int r = (u + 0x7fffu + ((u >> 16) & 1u)) >> 16;
    return (unsigned short)r;
}
__device__ inline float4 unpack_bf4(uint2 u) {
    float4 f;
    f.x = __uint_as_float(u.x << 16);
    f.y = __uint_as_float(u.x & 0xffff0000u);
    f.z = __uint_as_float(u.y << 16);
    f.w = __uint_as_float(u.y & 0xffff0000u);
    return f;
}

// ------- x fp32 -> bf16 + zero bin counters + zero virtual rows + build wt -------
// wt[layer][n][k] bf16, k<64: Wl[k][n], k>=64: Wr[k-64][n]  (B-operand layout)
__global__ __launch_bounds__(256)
void convert_zero_kernel(const float4* __restrict__ xin, ushort4* __restrict__ xb,
                         int n4, int* __restrict__ bin_cnt,
                         unsigned int* __restrict__ xb_zrow,
                         unsigned int* __restrict__ h_zrow,
                         const float* __restrict__ Wl1, const float* __restrict__ Wr1,
                         const float* __restrict__ Wl2, const float* __restrict__ Wr2,
                         unsigned short* __restrict__ wt) {
    int i = blockIdx.x * 256 + threadIdx.x;
    if (i < n4) {
        float4 v = xin[i];
        ushort4 u;
        u.x = f2bf(v.x); u.y = f2bf(v.y); u.z = f2bf(v.z); u.w = f2bf(v.w);
        xb[i] = u;
    }
    if (i < NBINS) bin_cnt[i] = 0;
    if (i < 32) { xb_zrow[i] = 0u; h_zrow[i] = 0u; }   // 64 bf16 = 32 uints each
    if (i < 2 * 64 * 128) {
        int layer = i >> 13;
        int n = (i >> 7) & 63;
        int k = i & 127;
        const float* W = layer ? (k < 64 ? Wl2 : Wr2) : (k < 64 ? Wl1 : Wr1);
        float v = W[(k & 63) * D + n];
        wt[i] = f2bf(v);
    }
}

// ---------------- pass 1: LDS-aggregated binning by dst>>9 ----------------
__global__ __launch_bounds__(256)
void bin_kernel(const int* __restrict__ src, const int* __restrict__ dst,
                int* __restrict__ bin_cnt, int* __restrict__ slabs) {
    __shared__ int lhist[NBINS];
    __shared__ int lstart[NBINS];
    __shared__ int lbase[NBINS];
    __shared__ int lcur[NBINS];
    __shared__ int pscan[256];
    __shared__ int sval[CHUNK];
    __shared__ int sdst[CHUNK];

    const int t = threadIdx.x;
    const int e0 = blockIdx.x * CHUNK;
    int cnt = N_EDGES - e0; if (cnt > CHUNK) cnt = CHUNK;

    for (int i = t; i < NBINS; i += 256) lhist[i] = 0;
    __syncthreads();

    for (int i = t; i < cnt; i += 256)
        atomicAdd(&lhist[dst[e0 + i] >> BIN_SHIFT], 1);
    __syncthreads();

    int h = (t < NBINS) ? lhist[t] : 0;
    pscan[t] = h;
    __syncthreads();
    for (int off = 1; off < 256; off <<= 1) {
        int x = (t >= off) ? pscan[t - off] : 0;
        __syncthreads();
        pscan[t] += x;
        __syncthreads();
    }
    if (t < NBINS) {
        int excl = pscan[t] - h;
        lstart[t] = excl;
        lcur[t] = excl;
        lbase[t] = (h > 0) ? atomicAdd(&bin_cnt[t], h) : 0;
    }
    __syncthreads();

    for (int i = t; i < cnt; i += 256) {
        int d = dst[e0 + i];
        int s = src[e0 + i];
        int b = d >> BIN_SHIFT;
        int slot = atomicAdd(&lcur[b], 1);
        int rank = slot - lstart[b];
        sval[slot] = (s << BIN_SHIFT) | (d & (BIN_NODES - 1));
        int gp = lbase[b] + rank;
        sdst[slot] = (gp < BIN_CAP) ? (b * SLAB + gp) : -1;
    }
    __syncthreads();

    for (int i = t; i < cnt; i += 256) {
        int dd = sdst[i];
        if (dd >= 0) slabs[dd] = sval[i];
    }
}

// ---------------- pass 2: per-bin LDS counting sort -> padded CSR (in place) ----
__global__ __launch_bounds__(256)
void bin_sort_kernel(int* __restrict__ slabs, const int* __restrict__ bin_cnt,
                     int* __restrict__ deg_out, int* __restrict__ rstart_out) {
    __shared__ int hist[BIN_NODES];
    __shared__ int cur[BIN_NODES];
    __shared__ int pscan[256];
    __shared__ int stage[BIN_CAP];

    const int b = blockIdx.x;
    const int t = threadIdx.x;
    int cnt = bin_cnt[b]; if (cnt > BIN_CAP) cnt = BIN_CAP;
    const int nb0 = b << BIN_SHIFT;
    const int nn = (N_NODES - nb0 < BIN_NODES) ? (N_NODES - nb0) : BIN_NODES;
    const int slab0 = b * SLAB;

    hist[t] = 0; hist[t + 256] = 0;
    __syncthreads();

    for (int i = t; i < cnt; i += 256) {
        int p = slabs[slab0 + i];
        stage[i] = p;
        atomicAdd(&hist[p & (BIN_NODES - 1)], 1);
    }
    __syncthreads();

    int h0 = hist[2 * t], h1 = hist[2 * t + 1];
    int ph0 = (h0 + 3) & ~3, ph1 = (h1 + 3) & ~3;
    int pv = ph0 + ph1;
    pscan[t] = pv;
    __syncthreads();
    for (int off = 1; off < 256; off <<= 1) {
        int x = (t >= off) ? pscan[t - off] : 0;
        __syncthreads();
        pscan[t] += x;
        __syncthreads();
    }
    int pairExcl = pscan[t] - pv;
    int s0 = pairExcl, s1 = pairExcl + ph0;
    cur[2 * t] = s0;
    cur[2 * t + 1] = s1;
    if (2 * t < nn) {
        deg_out[nb0 + 2 * t] = h0;
        rstart_out[nb0 + 2 * t] = slab0 + s0;
        for (int i = h0; i < ph0; ++i) slabs[slab0 + s0 + i] = ZERO_NODE;
    }
    if (2 * t + 1 < nn) {
        deg_out[nb0 + 2 * t + 1] = h1;
        rstart_out[nb0 + 2 * t + 1] = slab0 + s1;
        for (int i = h1; i < ph1; ++i) slabs[slab0 + s1 + i] = ZERO_NODE;
    }
    __syncthreads();

    for (int i = t; i < cnt; i += 256) {
        int p = stage[i];
        int pos = atomicAdd(&cur[p & (BIN_NODES - 1)], 1);
        slabs[slab0 + pos] = p >> BIN_SHIFT;
    }
}

// ---------------- fused layer: gather-mean + MFMA GEMM ----------------
// Gather: quad-edge (uint2/lane, 16 lanes/row), padded-x4 edge lists.
// GEMM: C[32,64] = [mean|x]_bf16[32,128] @ wt[128,64] + b  via
// mfma_f32_16x16x32_bf16 (8 tiles, 4 waves x 2 tiles x 4 K-steps).
// sA = bf16 [32][136] (8.7 KB LDS), 8 blocks/CU.
template <typename TOUT>
__global__ __launch_bounds__(256, 8)
void fused_layer_kernel(const unsigned short* __restrict__ xin,   // bf16 [N+1,D]
                        const int* __restrict__ rstart,
                        const int* __restrict__ deg,
                        const int* __restrict__ sorted_src,
                        const unsigned short* __restrict__ wt,    // bf16 [64][128]
                        const float* __restrict__ bl,
                        TOUT* __restrict__ out,
                        int relu) {
    __shared__ __align__(16) unsigned short sA[32][136];   // [row][k: 0-63 mean | 64-127 x]

    const uint2* __restrict__ xin64 = (const uint2*)xin;   // row = 16 uint2

    const int tid = threadIdx.x;
    const int row0 = blockIdx.x * 32;

    const int wave = tid >> 6;
    const int lane = tid & 63;
    const int q  = lane >> 4;
    const int f2 = lane & 15;

    for (int r = wave; r < 32; r += 4) {
        int n = row0 + r;
        float4 a = make_float4(0.f, 0.f, 0.f, 0.f);
        int dg = deg[n];
        int pdg = (dg + 3) & ~3;
        int st = rstart[n];
        uint2 xraw = xin64[(size_t)n * 16 + f2];

        for (int base = 0; base < pdg; base += 64) {
            int m = pdg - base; if (m > 64) m = 64;
            int idx = 0;
            if (lane < m) idx = sorted_src[st + base + lane];
            int quads = m >> 2;
            float4 c0 = make_float4(0.f, 0.f, 0.f, 0.f);
            float4 c1 = make_float4(0.f, 0.f, 0.f, 0.f);
            float4 c2 = make_float4(0.f, 0.f, 0.f, 0.f);
            float4 c3 = make_float4(0.f, 0.f, 0.f, 0.f);
            int t = 0;
            for (; t + 4 <= quads; t += 4) {
                int sA_ = __shfl(idx, 4 * t + q);
                int sB_ = __shfl(idx, 4 * t + 4 + q);
                int sC_ = __shfl(idx, 4 * t + 8 + q);
                int sD_ = __shfl(idx, 4 * t + 12 + q);
                float4 fA = unpack_bf4(xin64[(size_t)sA_ * 16 + f2]);
                float4 fB = unpack_bf4(xin64[(size_t)sB_ * 16 + f2]);
                float4 fC = unpack_bf4(xin64[(size_t)sC_ * 16 + f2]);
                float4 fD = unpack_bf4(xin64[(size_t)sD_ * 16 + f2]);
                c0.x += fA.x; c0.y += fA.y; c0.z += fA.z; c0.w += fA.w;
                c1.x += fB.x; c1.y += fB.y; c1.z += fB.z; c1.w += fB.w;
                c2.x += fC.x; c2.y += fC.y; c2.z += fC.z; c2.w += fC.w;
                c3.x += fD.x; c3.y += fD.y; c3.z += fD.z; c3.w += fD.w;
            }
            for (; t + 2 <= quads; t += 2) {
                int sA_ = __shfl(idx, 4 * t + q);
                int sB_ = __shfl(idx, 4 * t + 4 + q);
                float4 fA = unpack_bf4(xin64[(size_t)sA_ * 16 + f2]);
                float4 fB = unpack_bf4(xin64[(size_t)sB_ * 16 + f2]);
                c0.x += fA.x; c0.y += fA.y; c0.z += fA.z; c0.w += fA.w;
                c1.x += fB.x; c1.y += fB.y; c1.z += fB.z; c1.w += fB.w;
            }
            for (; t < quads; ++t) {
                int sA_ = __shfl(idx, 4 * t + q);
                float4 fA = unpack_bf4(xin64[(size_t)sA_ * 16 + f2]);
                c0.x += fA.x; c0.y += fA.y; c0.z += fA.z; c0.w += fA.w;
            }
            a.x += (c0.x + c1.x) + (c2.x + c3.x);
            a.y += (c0.y + c1.y) + (c2.y + c3.y);
            a.z += (c0.z + c1.z) + (c2.z + c3.z);
            a.w += (c0.w + c1.w) + (c2.w + c3.w);
        }

        a.x += __shfl_xor(a.x, 16); a.y += __shfl_xor(a.y, 16);
        a.z += __shfl_xor(a.z, 16); a.w += __shfl_xor(a.w, 16);
        a.x += __shfl_xor(a.x, 32); a.y += __shfl_xor(a.y, 32);
        a.z += __shfl_xor(a.z, 32); a.w += __shfl_xor(a.w, 32);

        float inv = 1.0f / (float)(dg > 0 ? dg : 1);
        if (q == 0) {
            unsigned int p0 = (unsigned int)f2bf(a.x * inv) |
                              ((unsigned int)f2bf(a.y * inv) << 16);
            unsigned int p1 = (unsigned int)f2bf(a.z * inv) |
                              ((unsigned int)f2bf(a.w * inv) << 16);
            *(uint2*)&sA[r][f2 * 4] = make_uint2(p0, p1);
            *(uint2*)&sA[r][64 + f2 * 4] = xraw;
        }
    }
    __syncthreads();

    // ---- MFMA GEMM phase ----
    const int tm = wave & 1;                 // tile row (0..1)
    const int tn0 = (wave >> 1) * 2;         // first tile col of this wave
    const int mrow = tm * 16 + (lane & 15);  // A row for this lane
    const int kq = (lane >> 4) * 8;          // k sub-offset within 32-chunk

    short8 afr[4];
#pragma unroll
    for (int kk = 0; kk < 4; ++kk)
        afr[kk] = *(const short8*)&sA[mrow][kk * 32 + kq];

#pragma unroll
    for (int ti = 0; ti < 2; ++ti) {
        const int tn = tn0 + ti;
        const int col = tn * 16 + (lane & 15);
        float bias = bl[col];
        f32x4 acc = {bias, bias, bias, bias};
#pragma unroll
        for (int kk = 0; kk < 4; ++kk) {
            short8 bfr = *(const short8*)&wt[col * 128 + kk * 32 + kq];
            acc = __builtin_amdgcn_mfma_f32_16x16x32_bf16(afr[kk], bfr, acc, 0, 0, 0);
        }
        const int r0 = row0 + tm * 16 + (lane >> 4) * 4;
#pragma unroll
        for (int reg = 0; reg < 4; ++reg) {
            float o = relu ? fmaxf(acc[reg], 0.f) : acc[reg];
            if constexpr (__hip_internal::is_same<TOUT, unsigned short>::value)
                out[(size_t)(r0 + reg) * D + col] = f2bf(o);
            else
                out[(size_t)(r0 + reg) * D + col] = o;
        }
    }
}

extern "C" void kernel_launch(void* const* d_in, const int* in_sizes, int n_in,
                              void* d_out, int out_size, void* d_ws, size_t ws_size,
                              hipStream_t stream) {
    const float* x   = (const float*)d_in[0];
    const int*   ei  = (const int*)d_in[1];
    const float* Wl1 = (const float*)d_in[2];
    const float* b1  = (const float*)d_in[3];
    const float* Wr1 = (const float*)d_in[4];
    const float* Wl2 = (const float*)d_in[5];
    const float* b2  = (const float*)d_in[6];
    const float* Wr2 = (const float*)d_in[7];

    const int* src = ei;
    const int* dst = ei + N_EDGES;

    // ws layout (ints): slabs[196*8704] | bin_cnt[256] | deg[N] | rstart[N] |
    //                   wt[2][64][128] bf16 (8192 ints) | h_bf16[(N+1)*D]
    int* slabs   = (int*)d_ws;
    int* bin_cnt = slabs + (size_t)NBINS * SLAB;
    int* deg     = bin_cnt + 256;
    int* rstart  = deg + N_NODES;
    unsigned short* wt_all = (unsigned short*)(rstart + N_NODES);   // 16384 ushorts
    unsigned short* wt1 = wt_all;
    unsigned short* wt2 = wt_all + 64 * 128;
    unsigned short* h = wt_all + 2 * 64 * 128;   // [N+1, D] bf16
    float* out = (float*)d_out;
    unsigned short* xb = (unsigned short*)d_out;  // bf16 x scratch in d_out [N+1, D]

    const int dense_blocks = N_NODES / 32;   // 3125
    const int conv4 = N_NODES * D / 4;
    const int bin_blocks = (N_EDGES + CHUNK - 1) / CHUNK;   // 306

    convert_zero_kernel<<<(conv4 + 255) / 256, 256, 0, stream>>>(
        (const float4*)x, (ushort4*)xb, conv4, bin_cnt,
        (unsigned int*)(xb + (size_t)ZERO_NODE * D),
        (unsigned int*)(h + (size_t)ZERO_NODE * D),
        Wl1, Wr1, Wl2, Wr2, wt_all);

    bin_kernel<<<bin_blocks, 256, 0, stream>>>(src, dst, bin_cnt, slabs);
    bin_sort_kernel<<<NBINS, 256, 0, stream>>>(slabs, bin_cnt, deg, rstart);

    fused_layer_kernel<unsigned short><<<dense_blocks, 256, 0, stream>>>(
        xb, rstart, deg, slabs, wt1, b1, h, /*relu=*/1);
    fused_layer_kernel<float><<<dense_blocks, 256, 0, stream>>>(
        h, rstart, deg, slabs, wt2, b2, out, /*relu=*/0);
}